// Round 16
// baseline (298.263 us; speedup 1.0000x reference)
//
#include <hip/hip_runtime.h>
#include <hip/hip_bf16.h>
#include <math.h>

#define B_N   131072
#define D_DIM 64
#define P_N   32
#define H_DIM 64
#define TPB   256
#define GRIDX 64
#define SPB   (B_N / GRIDX)      // samples per block = 2048
#define NS    3                  // streams per wave
#define SPI   (4 * 16 * NS)      // 192 samples per full block-iter
#define FULLIT 10                // 10*192 = 1920
#define TOTIT  11                // + tail iter (128 samples, streams 0..1 only)

#define K_L2E 1.44269504088896340736f   // log2(e)
#define LN2F  0.693147180559945309f     // 1/K

typedef __attribute__((ext_vector_type(8))) short bf16x8;
typedef __attribute__((ext_vector_type(4))) float f32x4;

static __device__ __forceinline__ unsigned short bfbits(float f) {
    __hip_bfloat16 b = __float2bfloat16(f);
    unsigned short u; __builtin_memcpy(&u, &b, 2); return u;
}
static __device__ __forceinline__ float bf2f(unsigned short u) {
    return __uint_as_float(((unsigned)u) << 16);
}

// z [B][64] -> zT [64][B]
__global__ void transpose_z(const float* __restrict__ z, float* __restrict__ zT) {
    __shared__ float tile[64][65];
    const int s0 = blockIdx.x * 64;
    const int t  = threadIdx.x;
    #pragma unroll
    for (int it = 0; it < 4; ++it) {
        int r  = it * 16 + (t >> 4);
        int c4 = (t & 15) * 4;
        const float4 v = *(const float4*)&z[(long)(s0 + r) * 64 + c4];
        tile[r][c4 + 0] = v.x; tile[r][c4 + 1] = v.y;
        tile[r][c4 + 2] = v.z; tile[r][c4 + 3] = v.w;
    }
    __syncthreads();
    #pragma unroll
    for (int it = 0; it < 16; ++it) {
        int d = it * 4 + (t >> 6);
        int s = t & 63;
        zT[d * B_N + s0 + s] = tile[s][d];
    }
}

// W2 [64][64] -> bf16 hi/lo planes in MFMA B-fragment-ready layout.
__global__ void prep_weights(const float* __restrict__ W2,
                             unsigned short* __restrict__ w2hi,
                             unsigned short* __restrict__ w2lo) {
    int t = blockIdx.x * blockDim.x + threadIdx.x;   // 0..4095
    int m = t & 7, l = (t >> 3) & 63, n = (t >> 9) & 3, c = t >> 11;
    int k = c * 32 + (l >> 4) * 8 + m;
    int col = n * 16 + (l & 15);
    float v = W2[k * 64 + col];
    unsigned short hi = bfbits(v);
    unsigned short lo = bfbits(v - bf2f(hi));
    w2hi[t] = hi;
    w2lo[t] = lo;
}

// K-folded elu via med3: K*(2^x-1) >= x (equality at 0) -> med3 selects the
// correct branch bit-exactly in 3 VALU ops.
static __device__ __forceinline__ float eluK(float xk) {
    float neg = fmaf(__builtin_amdgcn_exp2f(xk), K_L2E, -K_L2E);
    return __builtin_amdgcn_fmed3f(xk, neg, 0.0f);
}

union Frag { unsigned u[4]; bf16x8 v; };

// TR=1: zp is zT [64][B]. TR=0: zp is z [B][64].
// ET=0 (joint): w3 scaled by ln2 -> true score. ET=1 (marg): sc=K*score,
// exp(score)=exp2(sc). Weights in LDS; NS=3 streams; tail iter uses 2.
template<int ET, int TR>
__global__ __launch_bounds__(TPB, 3)
void mine_mfma(const float* __restrict__ zp,
               const float* __restrict__ W1, const float* __restrict__ b1,
               const unsigned short* __restrict__ w2hi,
               const unsigned short* __restrict__ w2lo,
               const float* __restrict__ b2,
               const float* __restrict__ W3,
               const int* __restrict__ pairs, const int* __restrict__ perms,
               double* __restrict__ partials) {
    const int wg = blockIdx.x;
    const int lg = (wg & 7) * (P_N * GRIDX / 8) + (wg >> 3);
    const int p  = lg >> 6;
    const int bx = lg & (GRIDX - 1);

    const int i    = pairs[2 * p];
    const int j    = pairs[2 * p + 1];
    const int tid  = threadIdx.x;
    const int lane = tid & 63;
    const int wv   = tid >> 6;
    const int g    = lane >> 4;
    const int r16  = lane & 15;

    #define ZA(idx) (TR ? zp[(long)i * B_N + (idx)] : zp[(long)(idx) * 64 + i])
    #define ZB(idx) (TR ? zp[(long)j * B_N + (idx)] : zp[(long)(idx) * 64 + j])

    // ---- LDS: W2 frags (16 KB) + K-scaled layer-1 weights (768 B)
    __shared__ bf16x8 w2s[1024];                 // [0..511]=hi, [512..1023]=lo
    __shared__ float  w1s[3][2][4][8];           // [a/b/bias][c][g][m]
    {
        const bf16x8* gh = (const bf16x8*)w2hi;
        const bf16x8* gl = (const bf16x8*)w2lo;
        #pragma unroll
        for (int q = 0; q < 4; ++q) {
            int idx = q * TPB + tid;
            w2s[idx] = (idx < 512) ? gh[idx] : gl[idx - 512];
        }
        if (tid < 64) {
            int cc = tid >> 5, gg = (tid >> 3) & 3, mm = tid & 7;
            w1s[0][cc][gg][mm] = W1[tid]      * K_L2E;
            w1s[1][cc][gg][mm] = W1[64 + tid] * K_L2E;
            w1s[2][cc][gg][mm] = b1[tid]      * K_L2E;
        }
    }

    float b2v[4], w3v[4];
    #pragma unroll
    for (int n = 0; n < 4; ++n) {
        b2v[n] = b2[n * 16 + r16] * K_L2E;
        w3v[n] = ET ? W3[n * 16 + r16]
                    : W3[n * 16 + r16] * LN2F;
    }

    __syncthreads();

    const int  sbase = bx * SPB + wv * 16 + r16;
    const int* pperm = perms + (long)p * B_N;

    // sample index for (iter t, stream u); tail iter (t==FULLIT) covers the
    // last 128 samples with streams 0..1. For prefetch of the (invalid)
    // tail stream 2, clamp to stream 1 (loaded, never accumulated).
    auto sidx = [&](int t, int u) -> int {
        int uu = (t >= FULLIT && u > 1) ? 1 : u;
        int base = (t < FULLIT) ? t * SPI : FULLIT * SPI;
        return sbase + base + uu * 64;
    };

    // ---- 3-deep pipeline: perm idx resident one iter before its gather ----
    float aC[NS], bC[NS], aN[NS], bN[NS];
    int   pmN2[NS];
    #pragma unroll
    for (int u = 0; u < NS; ++u) {
        const int s0 = sidx(0, u);
        const int s1 = sidx(1, u);
        int pm0 = ET ? pperm[s0] : s0;
        int pm1 = ET ? pperm[s1] : s1;
        bC[u] = ZB(s0);  aC[u] = ZA(pm0);
        bN[u] = ZB(s1);  aN[u] = ZA(pm1);
        int s2 = sidx(2, u);
        pmN2[u] = ET ? pperm[s2] : s2;
    }

    double acd[NS] = {0.0, 0.0, 0.0};

    for (int t = 0; t < TOTIT; ++t) {
        const int t2 = (t + 2 < TOTIT) ? t + 2 : TOTIT - 1;
        const int t3 = (t + 3 < TOTIT) ? t + 3 : TOTIT - 1;
        int   pmN3[NS];
        float bN2[NS], aN2[NS];
        #pragma unroll
        for (int u = 0; u < NS; ++u) {
            int s3 = sidx(t3, u);
            pmN3[u] = ET ? pperm[s3] : s3;
            bN2[u]  = ZB(sidx(t2, u));
            aN2[u]  = ZA(pmN2[u]);        // index loaded last iter: no wait
        }

        // layer 1, all streams; w1 from LDS (float4 broadcast per g-group)
        Frag ah[NS][2], al[NS][2];
        #pragma unroll
        for (int c = 0; c < 2; ++c) {
            const float4 wa0 = *(const float4*)&w1s[0][c][g][0];
            const float4 wa1 = *(const float4*)&w1s[0][c][g][4];
            const float4 wb0 = *(const float4*)&w1s[1][c][g][0];
            const float4 wb1 = *(const float4*)&w1s[1][c][g][4];
            const float4 bb0 = *(const float4*)&w1s[2][c][g][0];
            const float4 bb1 = *(const float4*)&w1s[2][c][g][4];
            const float wa[8] = {wa0.x, wa0.y, wa0.z, wa0.w, wa1.x, wa1.y, wa1.z, wa1.w};
            const float wb[8] = {wb0.x, wb0.y, wb0.z, wb0.w, wb1.x, wb1.y, wb1.z, wb1.w};
            const float bb[8] = {bb0.x, bb0.y, bb0.z, bb0.w, bb1.x, bb1.y, bb1.z, bb1.w};
            #pragma unroll
            for (int u = 0; u < NS; ++u)
                #pragma unroll
                for (int w = 0; w < 4; ++w) {
                    float pe = fmaf(aC[u], wa[2*w],   fmaf(bC[u], wb[2*w],   bb[2*w]));
                    float po = fmaf(aC[u], wa[2*w+1], fmaf(bC[u], wb[2*w+1], bb[2*w+1]));
                    float he = eluK(pe);
                    float ho = eluK(po);
                    unsigned ue = __float_as_uint(he), uo = __float_as_uint(ho);
                    ah[u][c].u[w] = __builtin_amdgcn_perm(uo, ue, 0x07060302u);
                    float le = he - __uint_as_float(ue & 0xFFFF0000u);
                    float lf = ho - __uint_as_float(uo & 0xFFFF0000u);
                    al[u][c].u[w] = __builtin_amdgcn_perm(__float_as_uint(lf),
                                                          __float_as_uint(le), 0x07060302u);
                }
        }

        // keep LDS reads inside the loop (defeat LICM re-hoist to registers)
        asm volatile("" ::: "memory");

        // layer 2: per-n frag staging from LDS; per-acc MFMA order fixed
        // (c0{hh,hl,lh}, c1{hh,hl,lh}) -> bit-identical across NS changes.
        f32x4 acc[NS][4];
        #pragma unroll
        for (int u = 0; u < NS; ++u)
            #pragma unroll
            for (int n = 0; n < 4; ++n)
                acc[u][n] = (f32x4){b2v[n], b2v[n], b2v[n], b2v[n]};
        #pragma unroll
        for (int n = 0; n < 4; ++n) {
            bf16x8 wh0 = w2s[      n * 64 + lane];
            bf16x8 wl0 = w2s[512 + n * 64 + lane];
            bf16x8 wh1 = w2s[      (4 + n) * 64 + lane];
            bf16x8 wl1 = w2s[512 + (4 + n) * 64 + lane];
            #pragma unroll
            for (int u = 0; u < NS; ++u) {
                acc[u][n] = __builtin_amdgcn_mfma_f32_16x16x32_bf16(ah[u][0].v, wh0, acc[u][n], 0, 0, 0);
                acc[u][n] = __builtin_amdgcn_mfma_f32_16x16x32_bf16(ah[u][0].v, wl0, acc[u][n], 0, 0, 0);
                acc[u][n] = __builtin_amdgcn_mfma_f32_16x16x32_bf16(al[u][0].v, wh0, acc[u][n], 0, 0, 0);
                acc[u][n] = __builtin_amdgcn_mfma_f32_16x16x32_bf16(ah[u][1].v, wh1, acc[u][n], 0, 0, 0);
                acc[u][n] = __builtin_amdgcn_mfma_f32_16x16x32_bf16(ah[u][1].v, wl1, acc[u][n], 0, 0, 0);
                acc[u][n] = __builtin_amdgcn_mfma_f32_16x16x32_bf16(al[u][1].v, wh1, acc[u][n], 0, 0, 0);
            }
        }

        // epilogue + accumulate (stream 2 skipped on the tail iter)
        #pragma unroll
        for (int u = 0; u < NS; ++u) {
            float sc[4] = {0.f, 0.f, 0.f, 0.f};
            #pragma unroll
            for (int r = 0; r < 4; ++r)
                #pragma unroll
                for (int n = 0; n < 4; ++n)
                    sc[r] = fmaf(eluK(acc[u][n][r]), w3v[n], sc[r]);

            const bool active = (u < 2) || (t < FULLIT);
            if (ET == 0) {
                if (active)
                    acd[u] += (double)((sc[0] + sc[1]) + (sc[2] + sc[3]));
            } else {
                const bool o1 = lane & 1;
                float k01 = o1 ? sc[1] : sc[0];
                float s01 = o1 ? sc[0] : sc[1];
                float v01 = k01 + __shfl_xor(s01, 1, 64);
                float k23 = o1 ? sc[3] : sc[2];
                float s23 = o1 ? sc[2] : sc[3];
                float v23 = k23 + __shfl_xor(s23, 1, 64);
                const bool o2 = lane & 2;
                float kk = o2 ? v23 : v01;
                float ss = o2 ? v01 : v23;
                float v  = kk + __shfl_xor(ss, 2, 64);
                v += __shfl_xor(v, 4, 64);
                v += __shfl_xor(v, 8, 64);
                // v = K*score; exp(score) = exp2(v). b3 cancels exactly.
                float ev = __builtin_amdgcn_exp2f(v);
                if (active) acd[u] += (double)ev;
            }
        }

        #pragma unroll
        for (int u = 0; u < NS; ++u) {
            aC[u] = aN[u]; bC[u] = bN[u];
            aN[u] = aN2[u]; bN[u] = bN2[u];
            pmN2[u] = pmN3[u];
        }
    }

    double accd = (acd[0] + acd[1]) + acd[2];

    __shared__ double red[TPB];
    red[tid] = accd;
    __syncthreads();
    for (int s = TPB / 2; s > 0; s >>= 1) {
        if (tid < s) red[tid] += red[tid + s];
        __syncthreads();
    }
    if (tid == 0) {
        double v = (ET == 0) ? red[0] : red[0] * 0.25;   // marg counted 4x
        partials[ET * (P_N * GRIDX) + p * GRIDX + bx] = v;
    }
    #undef ZA
    #undef ZB
}

__global__ void mine_final(const double* __restrict__ partials, float* __restrict__ out) {
    int lane = threadIdx.x;
    double mi = 0.0;
    if (lane < P_N) {
        double sj = 0.0, sm = 0.0;
        for (int c = 0; c < GRIDX; ++c) {
            sj += partials[lane * GRIDX + c];
            sm += partials[P_N * GRIDX + lane * GRIDX + c];
        }
        mi = sj / (double)B_N - log(sm / (double)B_N);
    }
    #pragma unroll
    for (int off = 32; off > 0; off >>= 1) mi += __shfl_down(mi, off);
    if (lane == 0) out[0] = (float)(mi / (double)P_N);
}

extern "C" void kernel_launch(void* const* d_in, const int* in_sizes, int n_in,
                              void* d_out, int out_size, void* d_ws, size_t ws_size,
                              hipStream_t stream) {
    const float* z     = (const float*)d_in[0];
    const float* W1    = (const float*)d_in[1];
    const float* b1    = (const float*)d_in[2];
    const float* W2    = (const float*)d_in[3];
    const float* b2    = (const float*)d_in[4];
    const float* W3    = (const float*)d_in[5];
    const int*   pairs = (const int*)d_in[7];
    const int*   perms = (const int*)d_in[8];

    const size_t ZT_BYTES = (size_t)D_DIM * B_N * sizeof(float);     // 32 MB
    const bool   tr = ws_size >= ZT_BYTES + 65536;

    float* zT   = (float*)d_ws;
    char*  wb   = (char*)d_ws + (tr ? ZT_BYTES : 0);
    unsigned short* w2hi = (unsigned short*)wb;                      // 8 KB
    unsigned short* w2lo = (unsigned short*)(wb + 8192);             // 8 KB
    double* partials     = (double*)(wb + 16384);                    // 32 KB

    prep_weights<<<16, 256, 0, stream>>>(W2, w2hi, w2lo);

    dim3 grid(P_N * GRIDX, 1, 1);
    if (tr) {
        transpose_z<<<B_N / 64, 256, 0, stream>>>(z, zT);
        mine_mfma<0, 1><<<grid, TPB, 0, stream>>>(zT, W1, b1, w2hi, w2lo, b2, W3,
                                                  pairs, perms, partials);
        mine_mfma<1, 1><<<grid, TPB, 0, stream>>>(zT, W1, b1, w2hi, w2lo, b2, W3,
                                                  pairs, perms, partials);
    } else {
        mine_mfma<0, 0><<<grid, TPB, 0, stream>>>(z, W1, b1, w2hi, w2lo, b2, W3,
                                                  pairs, perms, partials);
        mine_mfma<1, 0><<<grid, TPB, 0, stream>>>(z, W1, b1, w2hi, w2lo, b2, W3,
                                                  pairs, perms, partials);
    }
    mine_final<<<1, 64, 0, stream>>>(partials, (float*)d_out);
}

// Round 17
// 289.017 us; speedup vs baseline: 1.0320x; 1.0320x over previous
//
#include <hip/hip_runtime.h>
#include <hip/hip_bf16.h>
#include <math.h>

#define B_N   131072
#define D_DIM 64
#define P_N   32
#define H_DIM 64
#define TPB   256
#define GRIDX 64
#define SPB   (B_N / GRIDX)      // samples per block = 2048
#define SPI   128                // samples per block-iter (4 waves * 16 * 2 streams)
#define ITERS (SPB / SPI)        // 16

#define K_L2E 1.44269504088896340736f   // log2(e)
#define LN2F  0.693147180559945309f     // 1/K

typedef __attribute__((ext_vector_type(8))) short bf16x8;
typedef __attribute__((ext_vector_type(4))) float f32x4;

static __device__ __forceinline__ unsigned short bfbits(float f) {
    __hip_bfloat16 b = __float2bfloat16(f);
    unsigned short u; __builtin_memcpy(&u, &b, 2); return u;
}
static __device__ __forceinline__ float bf2f(unsigned short u) {
    return __uint_as_float(((unsigned)u) << 16);
}

// z [B][64] -> zT [64][B]
__global__ void transpose_z(const float* __restrict__ z, float* __restrict__ zT) {
    __shared__ float tile[64][65];
    const int s0 = blockIdx.x * 64;
    const int t  = threadIdx.x;
    #pragma unroll
    for (int it = 0; it < 4; ++it) {
        int r  = it * 16 + (t >> 4);
        int c4 = (t & 15) * 4;
        const float4 v = *(const float4*)&z[(long)(s0 + r) * 64 + c4];
        tile[r][c4 + 0] = v.x; tile[r][c4 + 1] = v.y;
        tile[r][c4 + 2] = v.z; tile[r][c4 + 3] = v.w;
    }
    __syncthreads();
    #pragma unroll
    for (int it = 0; it < 16; ++it) {
        int d = it * 4 + (t >> 6);
        int s = t & 63;
        zT[d * B_N + s0 + s] = tile[s][d];
    }
}

// W2 [64][64] -> bf16 hi/lo planes in MFMA B-fragment-ready layout.
__global__ void prep_weights(const float* __restrict__ W2,
                             unsigned short* __restrict__ w2hi,
                             unsigned short* __restrict__ w2lo) {
    int t = blockIdx.x * blockDim.x + threadIdx.x;   // 0..4095
    int m = t & 7, l = (t >> 3) & 63, n = (t >> 9) & 3, c = t >> 11;
    int k = c * 32 + (l >> 4) * 8 + m;
    int col = n * 16 + (l & 15);
    float v = W2[k * 64 + col];
    unsigned short hi = bfbits(v);
    unsigned short lo = bfbits(v - bf2f(hi));
    w2hi[t] = hi;
    w2lo[t] = lo;
}

// K-folded elu via med3: K*(2^x-1) >= x (equality at 0) -> med3 selects the
// correct branch bit-exactly in 3 VALU ops.
static __device__ __forceinline__ float eluK(float xk) {
    float neg = fmaf(__builtin_amdgcn_exp2f(xk), K_L2E, -K_L2E);
    return __builtin_amdgcn_fmed3f(xk, neg, 0.0f);
}

union Frag { unsigned u[4]; bf16x8 v; };

// One eval-type's full block computation (R15 structure: NS=2 streams,
// weights in LDS, 3-deep pipeline). Shared memory passed in from the kernel
// so the two template instantiations share one allocation.
template<int ET, int TR>
static __device__ __forceinline__ void mine_body(
        int p, int bx,
        const float* __restrict__ zp,
        const float* __restrict__ W1, const float* __restrict__ b1,
        const unsigned short* __restrict__ w2hi,
        const unsigned short* __restrict__ w2lo,
        const float* __restrict__ b2, const float* __restrict__ W3,
        const int* __restrict__ perms,
        double* __restrict__ partials,
        int i, int j,
        bf16x8* w2s, float (*w1s)[2][4][8], double* red) {
    const int tid  = threadIdx.x;
    const int lane = tid & 63;
    const int wv   = tid >> 6;
    const int g    = lane >> 4;
    const int r16  = lane & 15;

    #define ZA(idx) (TR ? zp[(long)i * B_N + (idx)] : zp[(long)(idx) * 64 + i])
    #define ZB(idx) (TR ? zp[(long)j * B_N + (idx)] : zp[(long)(idx) * 64 + j])

    // ---- stage LDS: W2 frags (16 KB) + K-scaled layer-1 weights (768 B)
    {
        const bf16x8* gh = (const bf16x8*)w2hi;
        const bf16x8* gl = (const bf16x8*)w2lo;
        #pragma unroll
        for (int q = 0; q < 4; ++q) {
            int idx = q * TPB + tid;
            w2s[idx] = (idx < 512) ? gh[idx] : gl[idx - 512];
        }
        if (tid < 64) {
            int cc = tid >> 5, gg = (tid >> 3) & 3, mm = tid & 7;
            w1s[0][cc][gg][mm] = W1[tid]      * K_L2E;
            w1s[1][cc][gg][mm] = W1[64 + tid] * K_L2E;
            w1s[2][cc][gg][mm] = b1[tid]      * K_L2E;
        }
    }

    float b2v[4], w3v[4];
    #pragma unroll
    for (int n = 0; n < 4; ++n) {
        b2v[n] = b2[n * 16 + r16] * K_L2E;               // acc' = K*(h1.W2 + b2)
        w3v[n] = ET ? W3[n * 16 + r16]                   // marg: sc = K*score
                    : W3[n * 16 + r16] * LN2F;           // joint: sc = score
    }

    __syncthreads();                                     // LDS ready

    const int  sbase = bx * SPB + wv * 16 + r16;
    const int* pperm = perms + (long)p * B_N;
    #define SIDX(t, u) (sbase + (t) * SPI + (u) * 64)

    // ---- 3-deep pipeline: perm idx resident one iter before its gather ----
    float aC[2], bC[2], aN[2], bN[2];
    int   pmN2[2];
    #pragma unroll
    for (int u = 0; u < 2; ++u) {
        const int s0 = SIDX(0, u);
        const int s1 = SIDX(1, u);
        int pm0 = ET ? pperm[s0] : s0;
        int pm1 = ET ? pperm[s1] : s1;
        bC[u] = ZB(s0);  aC[u] = ZA(pm0);
        bN[u] = ZB(s1);  aN[u] = ZA(pm1);
        pmN2[u] = ET ? pperm[SIDX(2, u)] : SIDX(2, u);
    }

    double acd0 = 0.0, acd1 = 0.0;

    for (int t = 0; t < ITERS; ++t) {
        const int t2 = (t + 2 < ITERS) ? t + 2 : ITERS - 1;
        const int t3 = (t + 3 < ITERS) ? t + 3 : ITERS - 1;
        int   pmN3[2];
        float bN2[2], aN2[2];
        #pragma unroll
        for (int u = 0; u < 2; ++u) {
            pmN3[u] = ET ? pperm[SIDX(t3, u)] : SIDX(t3, u);
            bN2[u]  = ZB(SIDX(t2, u));
            aN2[u]  = ZA(pmN2[u]);        // index loaded last iter: no wait
        }

        // layer 1 both streams; w1 from LDS (float4 broadcast per g-group)
        Frag ah[2][2], al[2][2];          // [stream][c]
        #pragma unroll
        for (int c = 0; c < 2; ++c) {
            const float4 wa0 = *(const float4*)&w1s[0][c][g][0];
            const float4 wa1 = *(const float4*)&w1s[0][c][g][4];
            const float4 wb0 = *(const float4*)&w1s[1][c][g][0];
            const float4 wb1 = *(const float4*)&w1s[1][c][g][4];
            const float4 bb0 = *(const float4*)&w1s[2][c][g][0];
            const float4 bb1 = *(const float4*)&w1s[2][c][g][4];
            const float wa[8] = {wa0.x, wa0.y, wa0.z, wa0.w, wa1.x, wa1.y, wa1.z, wa1.w};
            const float wb[8] = {wb0.x, wb0.y, wb0.z, wb0.w, wb1.x, wb1.y, wb1.z, wb1.w};
            const float bb[8] = {bb0.x, bb0.y, bb0.z, bb0.w, bb1.x, bb1.y, bb1.z, bb1.w};
            #pragma unroll
            for (int u = 0; u < 2; ++u)
                #pragma unroll
                for (int w = 0; w < 4; ++w) {
                    float pe = fmaf(aC[u], wa[2*w],   fmaf(bC[u], wb[2*w],   bb[2*w]));
                    float po = fmaf(aC[u], wa[2*w+1], fmaf(bC[u], wb[2*w+1], bb[2*w+1]));
                    float he = eluK(pe);
                    float ho = eluK(po);
                    unsigned ue = __float_as_uint(he), uo = __float_as_uint(ho);
                    ah[u][c].u[w] = __builtin_amdgcn_perm(uo, ue, 0x07060302u);
                    float le = he - __uint_as_float(ue & 0xFFFF0000u);
                    float lf = ho - __uint_as_float(uo & 0xFFFF0000u);
                    al[u][c].u[w] = __builtin_amdgcn_perm(__float_as_uint(lf),
                                                          __float_as_uint(le), 0x07060302u);
                }
        }

        // keep LDS reads inside the loop (defeat LICM re-hoist to registers)
        asm volatile("" ::: "memory");

        // layer 2: per-n frag staging from LDS (4 transient frags live).
        // Per-acc MFMA order fixed: c0{hh,hl,lh}, c1{hh,hl,lh}.
        f32x4 acc[2][4];
        #pragma unroll
        for (int u = 0; u < 2; ++u)
            #pragma unroll
            for (int n = 0; n < 4; ++n)
                acc[u][n] = (f32x4){b2v[n], b2v[n], b2v[n], b2v[n]};
        #pragma unroll
        for (int n = 0; n < 4; ++n) {
            bf16x8 wh0 = w2s[      n * 64 + lane];
            bf16x8 wl0 = w2s[512 + n * 64 + lane];
            bf16x8 wh1 = w2s[      (4 + n) * 64 + lane];
            bf16x8 wl1 = w2s[512 + (4 + n) * 64 + lane];
            #pragma unroll
            for (int u = 0; u < 2; ++u) {
                acc[u][n] = __builtin_amdgcn_mfma_f32_16x16x32_bf16(ah[u][0].v, wh0, acc[u][n], 0, 0, 0);
                acc[u][n] = __builtin_amdgcn_mfma_f32_16x16x32_bf16(ah[u][0].v, wl0, acc[u][n], 0, 0, 0);
                acc[u][n] = __builtin_amdgcn_mfma_f32_16x16x32_bf16(al[u][0].v, wh0, acc[u][n], 0, 0, 0);
                acc[u][n] = __builtin_amdgcn_mfma_f32_16x16x32_bf16(ah[u][1].v, wh1, acc[u][n], 0, 0, 0);
                acc[u][n] = __builtin_amdgcn_mfma_f32_16x16x32_bf16(ah[u][1].v, wl1, acc[u][n], 0, 0, 0);
                acc[u][n] = __builtin_amdgcn_mfma_f32_16x16x32_bf16(al[u][1].v, wh1, acc[u][n], 0, 0, 0);
            }
        }

        // epilogue both streams
        float sc[2][4];
        #pragma unroll
        for (int u = 0; u < 2; ++u) {
            sc[u][0] = sc[u][1] = sc[u][2] = sc[u][3] = 0.f;
            #pragma unroll
            for (int r = 0; r < 4; ++r)
                #pragma unroll
                for (int n = 0; n < 4; ++n)
                    sc[u][r] = fmaf(eluK(acc[u][n][r]), w3v[n], sc[u][r]);
        }

        if (ET == 0) {
            acd0 += (double)((sc[0][0] + sc[0][1]) + (sc[0][2] + sc[0][3]));
            acd1 += (double)((sc[1][0] + sc[1][1]) + (sc[1][2] + sc[1][3]));
        } else {
            #pragma unroll
            for (int u = 0; u < 2; ++u) {
                const bool o1 = lane & 1;
                float k01 = o1 ? sc[u][1] : sc[u][0];
                float s01 = o1 ? sc[u][0] : sc[u][1];
                float v01 = k01 + __shfl_xor(s01, 1, 64);
                float k23 = o1 ? sc[u][3] : sc[u][2];
                float s23 = o1 ? sc[u][2] : sc[u][3];
                float v23 = k23 + __shfl_xor(s23, 1, 64);
                const bool o2 = lane & 2;
                float kk = o2 ? v23 : v01;
                float ss = o2 ? v01 : v23;
                float v  = kk + __shfl_xor(ss, 2, 64);
                v += __shfl_xor(v, 4, 64);
                v += __shfl_xor(v, 8, 64);
                // v = K*score; exp(score) = exp2(v). b3 cancels exactly in
                // mean(joint) - log(mean(exp(marg))).
                float ev = __builtin_amdgcn_exp2f(v);
                if (u == 0) acd0 += (double)ev;
                else        acd1 += (double)ev;
            }
        }

        #pragma unroll
        for (int u = 0; u < 2; ++u) {
            aC[u] = aN[u]; bC[u] = bN[u];
            aN[u] = aN2[u]; bN[u] = bN2[u];
            pmN2[u] = pmN3[u];
        }
    }

    double accd = acd0 + acd1;

    red[tid] = accd;
    __syncthreads();
    for (int s = TPB / 2; s > 0; s >>= 1) {
        if (tid < s) red[tid] += red[tid + s];
        __syncthreads();
    }
    if (tid == 0) {
        double v = (ET == 0) ? red[0] : red[0] * 0.25;   // marg counted 4x
        partials[ET * (P_N * GRIDX) + p * GRIDX + bx] = v;
    }
    #undef ZA
    #undef ZB
    #undef SIDX
}

// Block-level fusion: even/odd block groups run joint/marg paths. Each CU
// hosts both types, so joint's stall-free compute fills marg's gather
// latency bubbles (R9's wave-level fusion failed on register pressure;
// block-level keeps per-wave code identical to the split kernels).
template<int TR>
__global__ __launch_bounds__(TPB, 4)
void mine_fused(const float* __restrict__ zp,
                const float* __restrict__ W1, const float* __restrict__ b1,
                const unsigned short* __restrict__ w2hi,
                const unsigned short* __restrict__ w2lo,
                const float* __restrict__ b2,
                const float* __restrict__ W3,
                const int* __restrict__ pairs, const int* __restrict__ perms,
                double* __restrict__ partials) {
    // wg[2:0]=XCD (HW round-robin), wg[3]=eval type, wg[11:4]=work id.
    // Each XCD sees alternating joint/marg blocks; each owns 4 pairs.
    const int wg   = blockIdx.x;
    const int xcd  = wg & 7;
    const int et   = (wg >> 3) & 1;
    const int rest = wg >> 4;                       // 0..255
    const int lg   = xcd * (P_N * GRIDX / 8) + rest;
    const int p    = lg >> 6;
    const int bx   = lg & (GRIDX - 1);

    const int i = pairs[2 * p];
    const int j = pairs[2 * p + 1];

    __shared__ bf16x8 w2s[1024];                    // 16 KB
    __shared__ float  w1s[3][2][4][8];              // 768 B
    __shared__ double red[TPB];                     // 2 KB

    if (et == 0)
        mine_body<0, TR>(p, bx, zp, W1, b1, w2hi, w2lo, b2, W3, perms,
                         partials, i, j, w2s, w1s, red);
    else
        mine_body<1, TR>(p, bx, zp, W1, b1, w2hi, w2lo, b2, W3, perms,
                         partials, i, j, w2s, w1s, red);
}

__global__ void mine_final(const double* __restrict__ partials, float* __restrict__ out) {
    int lane = threadIdx.x;
    double mi = 0.0;
    if (lane < P_N) {
        double sj = 0.0, sm = 0.0;
        for (int c = 0; c < GRIDX; ++c) {
            sj += partials[lane * GRIDX + c];
            sm += partials[P_N * GRIDX + lane * GRIDX + c];
        }
        mi = sj / (double)B_N - log(sm / (double)B_N);
    }
    #pragma unroll
    for (int off = 32; off > 0; off >>= 1) mi += __shfl_down(mi, off);
    if (lane == 0) out[0] = (float)(mi / (double)P_N);
}

extern "C" void kernel_launch(void* const* d_in, const int* in_sizes, int n_in,
                              void* d_out, int out_size, void* d_ws, size_t ws_size,
                              hipStream_t stream) {
    const float* z     = (const float*)d_in[0];
    const float* W1    = (const float*)d_in[1];
    const float* b1    = (const float*)d_in[2];
    const float* W2    = (const float*)d_in[3];
    const float* b2    = (const float*)d_in[4];
    const float* W3    = (const float*)d_in[5];
    const int*   pairs = (const int*)d_in[7];
    const int*   perms = (const int*)d_in[8];

    const size_t ZT_BYTES = (size_t)D_DIM * B_N * sizeof(float);     // 32 MB
    const bool   tr = ws_size >= ZT_BYTES + 65536;

    float* zT   = (float*)d_ws;
    char*  wb   = (char*)d_ws + (tr ? ZT_BYTES : 0);
    unsigned short* w2hi = (unsigned short*)wb;                      // 8 KB
    unsigned short* w2lo = (unsigned short*)(wb + 8192);             // 8 KB
    double* partials     = (double*)(wb + 16384);                    // 32 KB

    prep_weights<<<16, 256, 0, stream>>>(W2, w2hi, w2lo);

    dim3 grid(2 * P_N * GRIDX, 1, 1);
    if (tr) {
        transpose_z<<<B_N / 64, 256, 0, stream>>>(z, zT);
        mine_fused<1><<<grid, TPB, 0, stream>>>(zT, W1, b1, w2hi, w2lo, b2, W3,
                                                pairs, perms, partials);
    } else {
        mine_fused<0><<<grid, TPB, 0, stream>>>(z, W1, b1, w2hi, w2lo, b2, W3,
                                                pairs, perms, partials);
    }
    mine_final<<<1, 64, 0, stream>>>(partials, (float*)d_out);
}